// Round 13
// baseline (422.745 us; speedup 1.0000x reference)
//
#include <hip/hip_runtime.h>
#include <hip/hip_bf16.h>

#define D 128
#define NK 16
#define BT (64*2048)
#define NTILES 512

typedef short bf16x8 __attribute__((ext_vector_type(8)));
typedef float f32x4 __attribute__((ext_vector_type(4)));

__device__ __forceinline__ unsigned short f2bf(float f) {
  unsigned u = __builtin_bit_cast(unsigned, f);
  unsigned r = (u + 0x7FFFu + ((u >> 16) & 1u)) >> 16;   // RTNE
  return (unsigned short)r;
}
__device__ __forceinline__ float bf2f(unsigned short h) {
  unsigned u = ((unsigned)h) << 16;
  return __builtin_bit_cast(float, u);
}
__device__ __forceinline__ unsigned cvtpk(float lo, float hi) {
  unsigned r;
  asm volatile("v_cvt_pk_bf16_f32 %0, %1, %2" : "=v"(r) : "v"(lo), "v"(hi));
  return r;
}

__global__ void zero_kernel(float* out, int* flags, int* cnt) {
  if (threadIdx.x == 0) { out[0] = 0.f; cnt[0] = 0; }
  if (threadIdx.x < NK) flags[threadIdx.x] = 0;
}

// 512 threads: 4 passes of 512 lanes x 16B cover 32KB
__device__ __forceinline__ void stage_tile(const unsigned short* gsrc, unsigned short* lds, int tid) {
#pragma unroll
  for (int c = 0; c < 4; ++c) {
    const int off = c * 4096 + tid * 8;  // u16 units
    __builtin_amdgcn_global_load_lds(
        (const __attribute__((address_space(1))) unsigned int*)(gsrc + off),
        (__attribute__((address_space(3))) unsigned int*)(lds + off), 16, 0, 0);
  }
}

// LDS overlay:
//  main : Albuf0[0,32768) Albuf1[32768,65536) pT[65536,74240) Lm[74240,82432)
//         ld_s[82432,82496) tci[82496,82500) mah2/red[82512,90704)
//  setup: per half (offset half*77824): A[0,67584) T1[67584,71808) L11[71808,76032)
//         dgl[76032,76544) invd[76544,77056)
#define SMEM_BYTES 155648
#define HALF_LDS 77824

__global__ __launch_bounds__(512, 1) void fused_kernel(const float* __restrict__ x,
                                                       const float* __restrict__ probs,
                                                       const float* __restrict__ sigma,
                                                       const float* __restrict__ mu,
                                                       unsigned short* __restrict__ WG,
                                                       float* __restrict__ VG,
                                                       float* __restrict__ LmuG,
                                                       float* __restrict__ ldG,
                                                       int* __restrict__ flags,
                                                       int* __restrict__ cnt,
                                                       float* __restrict__ out) {
  __shared__ __align__(16) char smem[SMEM_BYTES];
  const int tid = threadIdx.x;

  // ============ setup prologue: blocks 0..7, TWO states per block (half = tid>>8) ============
  // Both halves execute identical control flow -> block barriers are lockstep-safe.
  // Two independent chol/substitution chains per CU -> latency interleaving (R12 lesson:
  // setup is chain-latency-bound at full clock; more chains/SIMD is the only lever).
  if (blockIdx.x < 8) {
    const int half = tid >> 8;
    const int htid = tid & 255;
    const int k = blockIdx.x * 2 + half;
    char* base = smem + half * HALF_LDS;
    float (*A)[132]  = reinterpret_cast<float(*)[132]>(base);
    float (*T1)[33]  = reinterpret_cast<float(*)[33]>(base + 67584);
    float (*L11)[33] = reinterpret_cast<float(*)[33]>(base + 71808);
    float* dgl  = reinterpret_cast<float*>(base + 76032);
    float* invd = reinterpret_cast<float*>(base + 76544);
    float* Vk = VG + (size_t)k * D * D;        // Linv in GLOBAL (L2); upper zeroed below
    const float* S = sigma + (size_t)k * D * D;

    for (int t = htid; t < D * D / 4; t += 256) {
      const int r = (4 * t) >> 7, c = (4 * t) & 127;
      *reinterpret_cast<float4*>(&A[r][c]) = *reinterpret_cast<const float4*>(&S[4 * t]);
      *reinterpret_cast<float4*>(&Vk[4 * t]) = (float4){0.f, 0.f, 0.f, 0.f};
    }
    __syncthreads();

    for (int p = 0; p < 4; ++p) {
      const int pe = p * 32;
      if (htid < 32) {
        // wave-synchronous 32x32 Cholesky: lane r owns row r in w[32]
        float w[32];
#pragma unroll
        for (int q = 0; q < 8; ++q) {
          const float4 v = *reinterpret_cast<const float4*>(&A[pe + htid][pe + 4 * q]);
          w[4*q] = v.x; w[4*q+1] = v.y; w[4*q+2] = v.z; w[4*q+3] = v.w;
        }
        float mydiag = 1.f, myinv = 1.f;
#pragma unroll
        for (int j = 0; j < 32; ++j) {
          const float piv = __shfl(w[j], j);
          const float inv = rsqrtf(piv);
          if (htid == j) { w[j] = piv * inv; mydiag = piv * inv; myinv = inv; }
          else if (htid > j) w[j] *= inv;
          const float lrj = w[j];
#pragma unroll
          for (int c = j + 1; c < 32; ++c) {
            const float lcj = __shfl(w[j], c);
            if (htid >= c) w[c] = fmaf(-lrj, lcj, w[c]);
          }
        }
#pragma unroll
        for (int c = 0; c < 32; ++c) {
          L11[htid][c] = w[c];
          if (c <= htid) A[pe + htid][pe + c] = w[c];
        }
        dgl[pe + htid] = mydiag;
        invd[pe + htid] = myinv;
      }
      __syncthreads();
      if (p < 3) {
        {
          const int r = htid;
          if (htid < 128 && r >= pe + 32) {
            // panel solve: a <- L11^{-1} a (forward substitution)
            float a[32];
#pragma unroll
            for (int q = 0; q < 8; ++q) {
              const float4 v = *reinterpret_cast<const float4*>(&A[r][pe + 4 * q]);
              a[4*q] = v.x; a[4*q+1] = v.y; a[4*q+2] = v.z; a[4*q+3] = v.w;
            }
#pragma unroll
            for (int c = 0; c < 32; ++c) {
              float s = a[c];
#pragma unroll
              for (int q = 0; q < c; ++q) s = fmaf(-L11[c][q], a[q], s);
              a[c] = s * invd[pe + c];
            }
#pragma unroll
            for (int q = 0; q < 8; ++q) {
              const float4 v = {a[4*q], a[4*q+1], a[4*q+2], a[4*q+3]};
              *reinterpret_cast<float4*>(&A[r][pe + 4 * q]) = v;
            }
          }
        }
        __syncthreads();
        {
          // SYRK: 2 halves of chunks per row; reads solved panel rows from A (batched)
          const int nr = 96 - 32 * p;
          if (htid < nr * 2) {
            const int r = pe + 32 + (htid % nr);
            const int h2 = htid / nr;
            float a2[32];
#pragma unroll
            for (int q = 0; q < 8; ++q) {
              const float4 v = *reinterpret_cast<const float4*>(&A[r][pe + 4 * q]);
              a2[4*q] = v.x; a2[4*q+1] = v.y; a2[4*q+2] = v.z; a2[4*q+3] = v.w;
            }
            for (int c4 = ((pe + 32) >> 2) + h2; c4 <= (r >> 2); c4 += 2) {
              float dot0 = 0.f, dot1 = 0.f, dot2 = 0.f, dot3 = 0.f;
#pragma unroll
              for (int q = 0; q < 8; ++q) {
                const float4 l0 = *reinterpret_cast<const float4*>(&A[4 * c4 + 0][pe + 4 * q]);
                const float4 l1 = *reinterpret_cast<const float4*>(&A[4 * c4 + 1][pe + 4 * q]);
                const float4 l2 = *reinterpret_cast<const float4*>(&A[4 * c4 + 2][pe + 4 * q]);
                const float4 l3 = *reinterpret_cast<const float4*>(&A[4 * c4 + 3][pe + 4 * q]);
                dot0 = fmaf(a2[4*q], l0.x, fmaf(a2[4*q+1], l0.y, fmaf(a2[4*q+2], l0.z, fmaf(a2[4*q+3], l0.w, dot0))));
                dot1 = fmaf(a2[4*q], l1.x, fmaf(a2[4*q+1], l1.y, fmaf(a2[4*q+2], l1.z, fmaf(a2[4*q+3], l1.w, dot1))));
                dot2 = fmaf(a2[4*q], l2.x, fmaf(a2[4*q+1], l2.y, fmaf(a2[4*q+2], l2.z, fmaf(a2[4*q+3], l2.w, dot2))));
                dot3 = fmaf(a2[4*q], l3.x, fmaf(a2[4*q+1], l3.y, fmaf(a2[4*q+2], l3.z, fmaf(a2[4*q+3], l3.w, dot3))));
              }
              float4 av = *reinterpret_cast<float4*>(&A[r][4 * c4]);
              if (4 * c4 + 0 <= r) av.x -= dot0;
              if (4 * c4 + 1 <= r) av.y -= dot1;
              if (4 * c4 + 2 <= r) av.z -= dot2;
              if (4 * c4 + 3 <= r) av.w -= dot3;
              *reinterpret_cast<float4*>(&A[r][4 * c4]) = av;
            }
          }
        }
      }
      __syncthreads();
    }

    // diag-block triangular inverse (registerized, reads A LDS, writes Vk global)
    if (htid < 128) {
      const int c = htid, ci = c & 31, b0 = (c >> 5) << 5;
      float v[32];
#pragma unroll
      for (int i = 0; i < 32; ++i) v[i] = 0.f;
#pragma unroll
      for (int i = 0; i < 32; ++i) {
        if (i == ci) v[i] = invd[c];
        else if (i > ci) {
          float s = 0.f;
#pragma unroll
          for (int q = 0; q < 32; ++q)
            if (q < i && q >= ci) s = fmaf(A[b0 + i][b0 + q], v[q], s);
          v[i] = -s * invd[b0 + i];
        }
      }
#pragma unroll
      for (int i = 0; i < 32; ++i)
        if (i >= ci) Vk[(size_t)(b0 + i) * D + c] = v[i];
    }

    // off-diagonal Linv blocks: 3 levels, pairs SEQUENTIAL (T1 single buffer)
    for (int d = 1; d <= 3; ++d) {
      for (int pair = 0; pair < 4 - d; ++pair) {
        __syncthreads();
        const int i0 = (pair + d) << 5, j0 = pair << 5;
        const int r = htid >> 3;
        const int c4 = (htid & 7) << 2;
        {
          // phase A: M = L * V  (A from LDS, V from global)
          float m0 = 0.f, m1 = 0.f, m2 = 0.f, m3 = 0.f;
#pragma unroll 8
          for (int pp = 0; pp < d * 32; ++pp) {
            const float av = A[i0 + r][j0 + pp];
            const float4 vp = *reinterpret_cast<const float4*>(&Vk[(size_t)(j0 + pp) * D + j0 + c4]);
            m0 = fmaf(av, vp.x, m0); m1 = fmaf(av, vp.y, m1);
            m2 = fmaf(av, vp.z, m2); m3 = fmaf(av, vp.w, m3);
          }
          T1[r][c4] = m0; T1[r][c4 + 1] = m1; T1[r][c4 + 2] = m2; T1[r][c4 + 3] = m3;
        }
        __syncthreads();
        {
          // phase B: V_ij = -V_ii * M
          float m0 = 0.f, m1 = 0.f, m2 = 0.f, m3 = 0.f;
#pragma unroll 8
          for (int pp = 0; pp <= r; ++pp) {
            const float av = Vk[(size_t)(i0 + r) * D + i0 + pp];
            const float* tp = &T1[pp][c4];
            m0 = fmaf(av, tp[0], m0); m1 = fmaf(av, tp[1], m1);
            m2 = fmaf(av, tp[2], m2); m3 = fmaf(av, tp[3], m3);
          }
          const float4 v = {-m0, -m1, -m2, -m3};
          *reinterpret_cast<float4*>(&Vk[(size_t)(i0 + r) * D + j0 + c4]) = v;
        }
      }
    }
    __syncthreads();

    if (htid < 128) {
      const float* muk = mu + k * D;
      float s = 0.f;
#pragma unroll 8
      for (int i = 0; i < D; ++i) s = fmaf(Vk[(size_t)htid * D + i], muk[i], s);
      LmuG[k * D + htid] = s;
    }
    if (htid < 64) {
      float s = logf(dgl[htid]) + logf(dgl[htid + 64]);
      s += __shfl_xor(s, 32); s += __shfl_xor(s, 16);
      s += __shfl_xor(s, 8);  s += __shfl_xor(s, 4);
      s += __shfl_xor(s, 2);  s += __shfl_xor(s, 1);
      if (htid == 0) ldG[k] = s;
    }
    // bf16 Linv image, pre-swizzled (row&15) so linear global_load_lds lands swizzled
    for (int t = htid; t < D * D; t += 256) {
      const int j = t >> 7, i = t & 127;
      WG[(size_t)k * D * D + j * D + (i ^ ((j & 15) << 3))] = f2bf(Vk[(size_t)j * D + i]);
    }
    __syncthreads();
    if (htid == 0) {
      __threadfence();
      __hip_atomic_store(&flags[k], 1, __ATOMIC_RELEASE, __HIP_MEMORY_SCOPE_AGENT);
    }
    __syncthreads();
  }

  // ================= main phase (all blocks, dynamic tiles) =================
  unsigned short* Albuf0 = reinterpret_cast<unsigned short*>(smem);
  unsigned short* Albuf1 = reinterpret_cast<unsigned short*>(smem + 32768);
  unsigned short* pTl    = reinterpret_cast<unsigned short*>(smem + 65536);
  float* Lm   = reinterpret_cast<float*>(smem + 74240);   // resident
  float* ld_s = reinterpret_cast<float*>(smem + 82432);   // resident
  int*   tci  = reinterpret_cast<int*>(smem + 82496);
  float* mah2 = reinterpret_cast<float*>(smem + 82512);   // [2][2][256]
  float* red  = mah2;

  const int ln = tid & 63;
  const int wid = tid >> 6;
  const int jg = wid >> 2;
  const int bg = wid & 3;
  const int l15 = ln & 15, lg = ln >> 4;

  float vt = 0.f;
  bool waited = false;

  for (;;) {
    __syncthreads();
    if (tid == 0) tci[0] = atomicAdd(cnt, 1);
    __syncthreads();
    const int tile = tci[0];
    if (tile >= NTILES) break;
    const size_t p0 = (size_t)tile * 256;

    // B-fragments: direct global fp32 -> bf16 registers (overlaps the setup window)
    bf16x8 bv[4][4];
#pragma unroll
    for (int n = 0; n < 4; ++n) {
      const float* xr = &x[(p0 + bg * 64 + n * 16 + l15) * D];
#pragma unroll
      for (int ks = 0; ks < 4; ++ks) {
        const float4 f0 = *reinterpret_cast<const float4*>(&xr[ks * 32 + lg * 8]);
        const float4 f1 = *reinterpret_cast<const float4*>(&xr[ks * 32 + lg * 8 + 4]);
        union { bf16x8 v; unsigned u[4]; } t;
        t.u[0] = cvtpk(f0.x, f0.y); t.u[1] = cvtpk(f0.z, f0.w);
        t.u[2] = cvtpk(f1.x, f1.y); t.u[3] = cvtpk(f1.z, f1.w);
        bv[ks][n] = t.v;
      }
    }
    for (int t = tid; t < 256 * 16; t += 512)
      pTl[(t >> 4) * 17 + (t & 15)] = f2bf(probs[p0 * NK + t]);

    if (!waited) {
      if (tid < NK) {
        while (__hip_atomic_load(&flags[tid], __ATOMIC_ACQUIRE, __HIP_MEMORY_SCOPE_AGENT) == 0)
          __builtin_amdgcn_s_sleep(1);
      }
      waited = true;
      __syncthreads();
      for (int t = tid; t < NK * D; t += 512) Lm[t] = LmuG[t];
      if (tid < NK) ld_s[tid] = ldG[tid];
    }
    __syncthreads();
    stage_tile(WG, Albuf0, tid);
    __syncthreads();

    if (tid < 256) vt += 117.62413225f;   // 0.5*D*ln(2*pi); sum_k p_k == 1

    for (int k = 0; k < NK; ++k) {
      if (k < NK - 1)
        stage_tile(WG + (size_t)(k + 1) * D * D, ((k + 1) & 1) ? Albuf1 : Albuf0, tid);
      const unsigned short* Ab = (k & 1) ? Albuf1 : Albuf0;

      f32x4 acc[4][4];
#pragma unroll
      for (int m = 0; m < 4; ++m)
#pragma unroll
        for (int n = 0; n < 4; ++n) acc[m][n] = (f32x4){0.f, 0.f, 0.f, 0.f};

#pragma unroll
      for (int ks = 0; ks < 4; ++ks) {
        const int kbs = (ks * 32 + lg * 8) ^ (l15 << 3);
        bf16x8 av[4];
#pragma unroll
        for (int m = 0; m < 4; ++m)
          av[m] = *reinterpret_cast<const bf16x8*>(&Ab[(jg * 64 + m * 16 + l15) * 128 + kbs]);
#pragma unroll
        for (int m = 0; m < 4; ++m)
#pragma unroll
          for (int n = 0; n < 4; ++n)
            acc[m][n] = __builtin_amdgcn_mfma_f32_16x16x32_bf16(av[m], bv[ks][n], acc[m][n], 0, 0, 0);
      }

      float lmv[4][4];
      const int jb = jg * 64 + lg * 4;
#pragma unroll
      for (int m = 0; m < 4; ++m)
#pragma unroll
        for (int r = 0; r < 4; ++r) lmv[m][r] = Lm[k * D + jb + m * 16 + r];
#pragma unroll
      for (int n = 0; n < 4; ++n) {
        float s = 0.f;
#pragma unroll
        for (int m = 0; m < 4; ++m)
#pragma unroll
          for (int r = 0; r < 4; ++r) {
            const float y = acc[m][n][r] - lmv[m][r];
            s = fmaf(y, y, s);
          }
        s += __shfl_xor(s, 16);
        s += __shfl_xor(s, 32);
        if (ln < 16) mah2[((k & 1) * 2 + jg) * 256 + bg * 64 + n * 16 + ln] = s;
      }
      __syncthreads();

      if (tid < 256) {
        const float maha = mah2[((k & 1) * 2 + 0) * 256 + tid] + mah2[((k & 1) * 2 + 1) * 256 + tid];
        vt = fmaf(bf2f(pTl[tid * 17 + k]), fmaf(0.5f, maha, ld_s[k]), vt);
      }
    }
  }

  if (tid < 256) red[tid] = vt;
  __syncthreads();
  for (int s = 128; s > 0; s >>= 1) {
    if (tid < s) red[tid] += red[tid + s];
    __syncthreads();
  }
  if (tid == 0) atomicAdd(out, red[0] * (1.0f / 64.0f));
}

extern "C" void kernel_launch(void* const* d_in, const int* in_sizes, int n_in,
                              void* d_out, int out_size, void* d_ws, size_t ws_size,
                              hipStream_t stream) {
  const float* x     = (const float*)d_in[0];
  const float* mu    = (const float*)d_in[1];
  const float* sigma = (const float*)d_in[2];
  const float* probs = (const float*)d_in[3];
  float* out = (float*)d_out;

  unsigned short* WG = (unsigned short*)d_ws;          // 512 KB bf16 Linv images
  float* VG   = (float*)(WG + (size_t)NK * D * D);     // 1 MB fp32 Linv (setup scratch)
  float* LmuG = VG + (size_t)NK * D * D;               // 8 KB
  float* ldG  = LmuG + NK * D;                         // 64 B
  int* flags  = (int*)(ldG + NK);                      // 64 B
  int* cnt    = flags + NK;                            // 4 B

  zero_kernel<<<1, 64, 0, stream>>>(out, flags, cnt);
  fused_kernel<<<256, 512, 0, stream>>>(x, probs, sigma, mu, WG, VG, LmuG, ldG, flags, cnt, out);
}

// Round 14
// 220.644 us; speedup vs baseline: 1.9160x; 1.9160x over previous
//
#include <hip/hip_runtime.h>
#include <hip/hip_bf16.h>

#define D 128
#define NK 16
#define BT (64*2048)
#define NTILES 512   // point-tiles per group (each group covers ALL points for its 2 states)

typedef short bf16x8 __attribute__((ext_vector_type(8)));
typedef float f32x4 __attribute__((ext_vector_type(4)));

__device__ __forceinline__ unsigned short f2bf(float f) {
  unsigned u = __builtin_bit_cast(unsigned, f);
  unsigned r = (u + 0x7FFFu + ((u >> 16) & 1u)) >> 16;   // RTNE
  return (unsigned short)r;
}
__device__ __forceinline__ unsigned cvtpk(float lo, float hi) {
  unsigned r;
  asm volatile("v_cvt_pk_bf16_f32 %0, %1, %2" : "=v"(r) : "v"(lo), "v"(hi));
  return r;
}

// ---- dispatch 1: zero accumulators (graph-replay safe) ----
__global__ __launch_bounds__(256) void zero_kernel(float* SG, float* mG, float* cG,
                                                   int* cnt, float* out) {
  const int i = blockIdx.x * 256 + threadIdx.x;
  for (int t = i; t < NK * D * D; t += 256 * 256) SG[t] = 0.f;        // 16 x 128x128
  if (i < NK * D) mG[i] = 0.f;
  if (i < NK) cG[i] = 0.f;
  if (i < 8) cnt[i] = 0;
  if (i == 0) out[0] = 0.f;
}

// LDS overlay:
//  setup: A[128][132]@0 (67584) V[128][132]@67584 (67584) T[3][32][33]@135168 (12672)
//         L11[32][33]@147840 (4224) dgl@152064 invd@152576  -> 153088
//  main : xT u32 [128][128]@0 (65536, bf16 elem view [128][256] swizzled)
//         pW u16 [2][256]@65536  tcib@66560  red[512]@66624
#define SMEM_BYTES 153088

__global__ __launch_bounds__(512, 1) void fused_kernel(const float* __restrict__ x,
                                                       const float* __restrict__ probs,
                                                       const float* __restrict__ sigma,
                                                       const float* __restrict__ mu,
                                                       float* __restrict__ SG,
                                                       float* __restrict__ PG,
                                                       float* __restrict__ mG,
                                                       float* __restrict__ cG,
                                                       float* __restrict__ ldG,
                                                       int* __restrict__ cnt) {
  __shared__ __align__(16) char smem[SMEM_BYTES];
  const int tid = threadIdx.x;
  const int g = blockIdx.x >> 5;         // 8 groups x 32 blocks; group owns states {2g, 2g+1}
  const int w = blockIdx.x & 31;

  // ============ setup (2 blocks per group): chol -> Linv -> P = V^T V, logdet ============
  if (w < 2) {
    const int k = 2 * g + w;
    float (*A)[132]    = reinterpret_cast<float(*)[132]>(smem);
    float (*V)[132]    = reinterpret_cast<float(*)[132]>(smem + 67584);
    float (*T)[32][33] = reinterpret_cast<float(*)[32][33]>(smem + 135168);
    float (*L11)[33]   = reinterpret_cast<float(*)[33]>(smem + 147840);
    float* dgl  = reinterpret_cast<float*>(smem + 152064);
    float* invd = reinterpret_cast<float*>(smem + 152576);
    float* Tp   = reinterpret_cast<float*>(smem + 135168);   // [96][32] view
    const float* S = sigma + (size_t)k * D * D;

    for (int t = tid; t < D * D / 4; t += 512) {
      const int r = (4 * t) >> 7, c = (4 * t) & 127;
      *reinterpret_cast<float4*>(&A[r][c]) = *reinterpret_cast<const float4*>(&S[4 * t]);
    }
    for (int t = tid; t < D * D; t += 512) V[t >> 7][t & 127] = 0.f;
    __syncthreads();

    for (int p = 0; p < 4; ++p) {
      const int pe = p * 32;
      if (tid < 32) {
        float wv[32];
#pragma unroll
        for (int q = 0; q < 8; ++q) {
          const float4 v = *reinterpret_cast<const float4*>(&A[pe + tid][pe + 4 * q]);
          wv[4*q] = v.x; wv[4*q+1] = v.y; wv[4*q+2] = v.z; wv[4*q+3] = v.w;
        }
        float mydiag = 1.f, myinv = 1.f;
#pragma unroll
        for (int j = 0; j < 32; ++j) {
          const float piv = __shfl(wv[j], j);
          const float inv = rsqrtf(piv);
          if (tid == j) { wv[j] = piv * inv; mydiag = piv * inv; myinv = inv; }
          else if (tid > j) wv[j] *= inv;
          const float lrj = wv[j];
#pragma unroll
          for (int c = j + 1; c < 32; ++c) {
            const float lcj = __shfl(wv[j], c);
            if (tid >= c) wv[c] = fmaf(-lrj, lcj, wv[c]);
          }
        }
#pragma unroll
        for (int c = 0; c < 32; ++c) {
          L11[tid][c] = wv[c];
          if (c <= tid) A[pe + tid][pe + c] = wv[c];
        }
        dgl[pe + tid] = mydiag;
        invd[pe + tid] = myinv;
      }
      __syncthreads();
      if (p < 3) {
        {
          const int r = tid;
          if (tid < 128 && r >= pe + 32) {
            float a[32];
#pragma unroll
            for (int q = 0; q < 8; ++q) {
              const float4 v = *reinterpret_cast<const float4*>(&A[r][pe + 4 * q]);
              a[4*q] = v.x; a[4*q+1] = v.y; a[4*q+2] = v.z; a[4*q+3] = v.w;
            }
#pragma unroll
            for (int c = 0; c < 32; ++c) {
              float s = a[c];
#pragma unroll
              for (int q = 0; q < c; ++q) s = fmaf(-L11[c][q], a[q], s);
              a[c] = s * invd[pe + c];
            }
#pragma unroll
            for (int q = 0; q < 8; ++q) {
              const float4 v = {a[4*q], a[4*q+1], a[4*q+2], a[4*q+3]};
              *reinterpret_cast<float4*>(&A[r][pe + 4 * q]) = v;
              *reinterpret_cast<float4*>(&Tp[(r - pe - 32) * 32 + 4 * q]) = v;
            }
          }
        }
        __syncthreads();
        {
          const int nr = 96 - 32 * p;
          if (tid < nr * 4) {
            const int r = pe + 32 + (tid % nr);
            const int quarter = tid / nr;
            float a2[32];
#pragma unroll
            for (int q = 0; q < 8; ++q) {
              const float4 v = *reinterpret_cast<const float4*>(&Tp[(r - pe - 32) * 32 + 4 * q]);
              a2[4*q] = v.x; a2[4*q+1] = v.y; a2[4*q+2] = v.z; a2[4*q+3] = v.w;
            }
            for (int c4 = ((pe + 32) >> 2) + quarter; c4 <= (r >> 2); c4 += 4) {
              float dot0 = 0.f, dot1 = 0.f, dot2 = 0.f, dot3 = 0.f;
              const float* tb = &Tp[(4 * c4 - pe - 32) * 32];
#pragma unroll
              for (int q = 0; q < 8; ++q) {
                const float4 l0 = *reinterpret_cast<const float4*>(&tb[0 * 32 + 4 * q]);
                const float4 l1 = *reinterpret_cast<const float4*>(&tb[1 * 32 + 4 * q]);
                const float4 l2 = *reinterpret_cast<const float4*>(&tb[2 * 32 + 4 * q]);
                const float4 l3 = *reinterpret_cast<const float4*>(&tb[3 * 32 + 4 * q]);
                dot0 = fmaf(a2[4*q], l0.x, fmaf(a2[4*q+1], l0.y, fmaf(a2[4*q+2], l0.z, fmaf(a2[4*q+3], l0.w, dot0))));
                dot1 = fmaf(a2[4*q], l1.x, fmaf(a2[4*q+1], l1.y, fmaf(a2[4*q+2], l1.z, fmaf(a2[4*q+3], l1.w, dot1))));
                dot2 = fmaf(a2[4*q], l2.x, fmaf(a2[4*q+1], l2.y, fmaf(a2[4*q+2], l2.z, fmaf(a2[4*q+3], l2.w, dot2))));
                dot3 = fmaf(a2[4*q], l3.x, fmaf(a2[4*q+1], l3.y, fmaf(a2[4*q+2], l3.z, fmaf(a2[4*q+3], l3.w, dot3))));
              }
              float4 av = *reinterpret_cast<float4*>(&A[r][4 * c4]);
              if (4 * c4 + 0 <= r) av.x -= dot0;
              if (4 * c4 + 1 <= r) av.y -= dot1;
              if (4 * c4 + 2 <= r) av.z -= dot2;
              if (4 * c4 + 3 <= r) av.w -= dot3;
              *reinterpret_cast<float4*>(&A[r][4 * c4]) = av;
            }
          }
        }
      }
      __syncthreads();
    }

    if (tid < 128) {     // diag-block triangular inverse (registerized)
      const int c = tid, ci = c & 31, b0 = (c >> 5) << 5;
      float v[32];
#pragma unroll
      for (int i = 0; i < 32; ++i) v[i] = 0.f;
#pragma unroll
      for (int i = 0; i < 32; ++i) {
        if (i == ci) v[i] = invd[c];
        else if (i > ci) {
          float s = 0.f;
#pragma unroll
          for (int q = 0; q < 32; ++q)
            if (q < i && q >= ci) s = fmaf(A[b0 + i][b0 + q], v[q], s);
          v[i] = -s * invd[b0 + i];
        }
      }
#pragma unroll
      for (int i = 0; i < 32; ++i)
        if (i >= ci) V[b0 + i][c] = v[i];
    }

    for (int d = 1; d <= 3; ++d) {    // off-diagonal Linv blocks
      __syncthreads();
      const int npair = 4 - d;
      for (int q = tid; q < npair * 256; q += 512) {
        const int pair = q >> 8;
        const int r = (q >> 3) & 31;
        const int c4 = (q & 7) << 2;
        const int i0 = (pair + d) << 5, j0 = pair << 5;
        float m0 = 0.f, m1 = 0.f, m2 = 0.f, m3 = 0.f;
#pragma unroll 8
        for (int pp = 0; pp < d * 32; ++pp) {
          const float av = A[i0 + r][j0 + pp];
          const float* vp = &V[j0 + pp][j0 + c4];
          m0 = fmaf(av, vp[0], m0); m1 = fmaf(av, vp[1], m1);
          m2 = fmaf(av, vp[2], m2); m3 = fmaf(av, vp[3], m3);
        }
        T[pair][r][c4] = m0; T[pair][r][c4 + 1] = m1;
        T[pair][r][c4 + 2] = m2; T[pair][r][c4 + 3] = m3;
      }
      __syncthreads();
      for (int q = tid; q < npair * 256; q += 512) {
        const int pair = q >> 8;
        const int r = (q >> 3) & 31;
        const int c4 = (q & 7) << 2;
        const int i0 = (pair + d) << 5, j0 = pair << 5;
        float m0 = 0.f, m1 = 0.f, m2 = 0.f, m3 = 0.f;
#pragma unroll 8
        for (int pp = 0; pp <= r; ++pp) {
          const float av = V[i0 + r][i0 + pp];
          const float* tp = &T[pair][pp][c4];
          m0 = fmaf(av, tp[0], m0); m1 = fmaf(av, tp[1], m1);
          m2 = fmaf(av, tp[2], m2); m3 = fmaf(av, tp[3], m3);
        }
        V[i0 + r][j0 + c4] = -m0; V[i0 + r][j0 + c4 + 1] = -m1;
        V[i0 + r][j0 + c4 + 2] = -m2; V[i0 + r][j0 + c4 + 3] = -m3;
      }
    }
    __syncthreads();

    // P = V^T V (f32), register-blocked 4 rows x 8 cols per thread
    {
      const int i0 = (tid >> 4) * 4;          // 32 row-groups
      const int c0 = (tid & 15) * 8;          // 16 col-groups
      float pa[4][8];
#pragma unroll
      for (int a = 0; a < 4; ++a)
#pragma unroll
        for (int b = 0; b < 8; ++b) pa[a][b] = 0.f;
      for (int r = 0; r < D; ++r) {
        const float4 vi = *reinterpret_cast<const float4*>(&V[r][i0]);
        const float4 vc0 = *reinterpret_cast<const float4*>(&V[r][c0]);
        const float4 vc1 = *reinterpret_cast<const float4*>(&V[r][c0 + 4]);
        const float vis[4] = {vi.x, vi.y, vi.z, vi.w};
        const float vcs[8] = {vc0.x, vc0.y, vc0.z, vc0.w, vc1.x, vc1.y, vc1.z, vc1.w};
#pragma unroll
        for (int a = 0; a < 4; ++a)
#pragma unroll
          for (int b = 0; b < 8; ++b) pa[a][b] = fmaf(vis[a], vcs[b], pa[a][b]);
      }
      float* Pk = PG + (size_t)k * D * D;
#pragma unroll
      for (int a = 0; a < 4; ++a)
#pragma unroll
        for (int b = 0; b < 2; ++b) {
          const float4 v = {pa[a][4*b], pa[a][4*b+1], pa[a][4*b+2], pa[a][4*b+3]};
          *reinterpret_cast<float4*>(&Pk[(i0 + a) * D + c0 + 4 * b]) = v;
        }
    }
    if (tid < 64) {
      float s = logf(dgl[tid]) + logf(dgl[tid + 64]);
      s += __shfl_xor(s, 32); s += __shfl_xor(s, 16);
      s += __shfl_xor(s, 8);  s += __shfl_xor(s, 4);
      s += __shfl_xor(s, 2);  s += __shfl_xor(s, 1);
      if (tid == 0) ldG[k] = s;
    }
    __syncthreads();   // setup LDS dead; no flags needed (only dispatch 3 reads P/ld)
  }

  // ============ main: S_k = (p .* X)^T X over dynamic point-tiles, acc in AGPRs ============
  unsigned* xTu = reinterpret_cast<unsigned*>(smem);           // [d][tp^swz] u32 (2 points)
  unsigned short* xT16 = reinterpret_cast<unsigned short*>(smem);
  unsigned short* pW = reinterpret_cast<unsigned short*>(smem + 65536);  // [2][256] bf16
  int* tcib = reinterpret_cast<int*>(smem + 66560);
  float* red = reinterpret_cast<float*>(smem + 66624);          // [512]

  const int ln = tid & 63, wid = tid >> 6;
  const int myk = wid >> 2;                 // 0/1 : which of the group's two states
  const int q = wid & 3, qa = q >> 1, qb = q & 1;   // 64x64 quadrant of S
  const int l15 = ln & 15, lg = ln >> 4;
  const int kst = 2 * g + myk;

  f32x4 acc[4][4];
#pragma unroll
  for (int m = 0; m < 4; ++m)
#pragma unroll
    for (int n = 0; n < 4; ++n) acc[m][n] = (f32x4){0.f, 0.f, 0.f, 0.f};
  float macc[4] = {0.f, 0.f, 0.f, 0.f};
  float c0a = 0.f, c1a = 0.f;

  union U8 { bf16x8 v; unsigned u[4]; };

  for (;;) {
    __syncthreads();
    if (tid == 0) tcib[0] = atomicAdd(&cnt[g], 1);
    __syncthreads();
    const int tile = tcib[0];
    if (tile >= NTILES) break;
    const size_t p0 = (size_t)tile * 256;

    // stage xT (transposed bf16, point-pairs packed in u32, XOR-swizzled)
    {
      const int tp = tid & 127, d0 = (tid >> 7) * 32;
      const float* xr = &x[(p0 + 2 * tp) * D + d0];
      float4 v0[8], v1[8];
#pragma unroll
      for (int j = 0; j < 8; ++j) {
        v0[j] = *reinterpret_cast<const float4*>(&xr[4 * j]);
        v1[j] = *reinterpret_cast<const float4*>(&xr[D + 4 * j]);
      }
#pragma unroll
      for (int j = 0; j < 8; ++j) {
        const float l0[4] = {v0[j].x, v0[j].y, v0[j].z, v0[j].w};
        const float h0[4] = {v1[j].x, v1[j].y, v1[j].z, v1[j].w};
#pragma unroll
        for (int e = 0; e < 4; ++e) {
          const int d = d0 + 4 * j + e;
          xTu[d * 128 + (tp ^ ((d & 15) << 2))] = cvtpk(l0[e], h0[e]);
        }
      }
    }
    if (tid < 256) {
      const float2 pv = *reinterpret_cast<const float2*>(&probs[(p0 + tid) * NK + 2 * g]);
      c0a += pv.x; c1a += pv.y;
      pW[tid] = f2bf(pv.x); pW[256 + tid] = f2bf(pv.y);
    }
    __syncthreads();

#pragma unroll
    for (int ks = 0; ks < 8; ++ks) {
      const int tcol = ks * 32 + lg * 8;
      U8 pu; pu.v = *reinterpret_cast<const bf16x8*>(&pW[myk * 256 + tcol]);
      float pfv[8];
#pragma unroll
      for (int j = 0; j < 4; ++j) {
        pfv[2*j]   = __builtin_bit_cast(float, pu.u[j] << 16);
        pfv[2*j+1] = __builtin_bit_cast(float, pu.u[j] & 0xffff0000u);
      }
      bf16x8 aw[4], bv[4];
#pragma unroll
      for (int m = 0; m < 4; ++m) {
        const int d = qa * 64 + m * 16 + l15;
        U8 xu; xu.v = *reinterpret_cast<const bf16x8*>(&xT16[d * 256 + (tcol ^ (l15 << 3))]);
        U8 wv;
        float s = 0.f;
#pragma unroll
        for (int j = 0; j < 4; ++j) {
          const float lo = __builtin_bit_cast(float, xu.u[j] << 16);
          const float hi = __builtin_bit_cast(float, xu.u[j] & 0xffff0000u);
          const float wl = lo * pfv[2*j], wh = hi * pfv[2*j+1];
          wv.u[j] = cvtpk(wl, wh);
          s += wl + wh;
        }
        aw[m] = wv.v;
        if (qb == 0) macc[m] += s;       // m_k partial (each d counted once: qb==0 only)
      }
#pragma unroll
      for (int n = 0; n < 4; ++n) {
        const int d = qb * 64 + n * 16 + l15;
        bv[n] = *reinterpret_cast<const bf16x8*>(&xT16[d * 256 + (tcol ^ (l15 << 3))]);
      }
#pragma unroll
      for (int m = 0; m < 4; ++m)
#pragma unroll
        for (int n = 0; n < 4; ++n)
          acc[m][n] = __builtin_amdgcn_mfma_f32_16x16x32_bf16(aw[m], bv[n], acc[m][n], 0, 0, 0);
    }
  }

  // flush S partials (C-layout: col=lane&15, row=(lane>>4)*4+r)
  {
    float* Sk = SG + (size_t)kst * D * D;
#pragma unroll
    for (int m = 0; m < 4; ++m)
#pragma unroll
      for (int n = 0; n < 4; ++n)
#pragma unroll
        for (int r = 0; r < 4; ++r)
          atomicAdd(&Sk[(qa * 64 + m * 16 + lg * 4 + r) * D + qb * 64 + n * 16 + l15],
                    acc[m][n][r]);
  }
  // flush m partials
#pragma unroll
  for (int m = 0; m < 4; ++m) {
    float s = macc[m];
    s += __shfl_xor(s, 16);
    s += __shfl_xor(s, 32);
    if (qb == 0 && ln < 16) atomicAdd(&mG[kst * D + qa * 64 + m * 16 + ln], s);
  }
  // flush c partials
  red[tid] = c0a; __syncthreads();
  for (int s = 256; s > 0; s >>= 1) { if (tid < s) red[tid] += red[tid + s]; __syncthreads(); }
  if (tid == 0) atomicAdd(&cG[2 * g], red[0]);
  __syncthreads();
  red[tid] = c1a; __syncthreads();
  for (int s = 256; s > 0; s >>= 1) { if (tid < s) red[tid] += red[tid + s]; __syncthreads(); }
  if (tid == 0) atomicAdd(&cG[2 * g + 1], red[0]);
}

// ---- dispatch 3: per-state trace + corrections ----
__global__ __launch_bounds__(256) void final_kernel(const float* __restrict__ mu,
                                                    const float* __restrict__ SG,
                                                    const float* __restrict__ PG,
                                                    const float* __restrict__ mG,
                                                    const float* __restrict__ cG,
                                                    const float* __restrict__ ldG,
                                                    float* __restrict__ out) {
  __shared__ float u[D];
  __shared__ float red[256];
  const int k = blockIdx.x, tid = threadIdx.x;
  const float* P = PG + (size_t)k * D * D;
  const float* S = SG + (size_t)k * D * D;
  const float* muk = mu + k * D;

  if (tid < D) {
    float s = 0.f;
    for (int i = 0; i < D; ++i) s = fmaf(P[tid * D + i], muk[i], s);
    u[tid] = s;                       // u = P mu
  }
  __syncthreads();

  float tr = 0.f;
  for (int i = tid; i < D * D; i += 256) tr = fmaf(P[i], S[i], tr);
  red[tid] = tr; __syncthreads();
  for (int s = 128; s > 0; s >>= 1) { if (tid < s) red[tid] += red[tid + s]; __syncthreads(); }
  const float trPS = red[0];
  __syncthreads();

  red[tid] = (tid < D) ? mG[k * D + tid] * u[tid] : 0.f;   // m^T u
  __syncthreads();
  for (int s = 128; s > 0; s >>= 1) { if (tid < s) red[tid] += red[tid + s]; __syncthreads(); }
  const float mtu = red[0];
  __syncthreads();

  red[tid] = (tid < D) ? muk[tid] * u[tid] : 0.f;          // mu^T u
  __syncthreads();
  for (int s = 128; s > 0; s >>= 1) { if (tid < s) red[tid] += red[tid + s]; __syncthreads(); }
  const float muu = red[0];

  if (tid == 0) {
    const float c = cG[k];
    float term = 0.5f * (trPS - 2.f * mtu + c * muu) + c * ldG[k];
    if (k == 0) term += 117.62413225f * (float)BT;         // 0.5*D*ln(2pi) * sum_k c_k
    atomicAdd(out, term * (1.0f / 64.0f));
  }
}

extern "C" void kernel_launch(void* const* d_in, const int* in_sizes, int n_in,
                              void* d_out, int out_size, void* d_ws, size_t ws_size,
                              hipStream_t stream) {
  const float* x     = (const float*)d_in[0];
  const float* mu    = (const float*)d_in[1];
  const float* sigma = (const float*)d_in[2];
  const float* probs = (const float*)d_in[3];
  float* out = (float*)d_out;

  float* SG  = (float*)d_ws;                       // 16*128*128 f32 = 1 MB
  float* PG  = SG + (size_t)NK * D * D;            // 1 MB
  float* mG  = PG + (size_t)NK * D * D;            // 8 KB
  float* cG  = mG + NK * D;                        // 64 B
  float* ldG = cG + NK;                            // 64 B
  int* cnt   = (int*)(ldG + NK);                   // 32 B

  zero_kernel<<<256, 256, 0, stream>>>(SG, mG, cG, cnt, out);
  fused_kernel<<<256, 512, 0, stream>>>(x, probs, sigma, mu, SG, PG, mG, cG, ldG, cnt);
  final_kernel<<<NK, 256, 0, stream>>>(mu, SG, PG, mG, cG, ldG, out);
}